// Round 1
// baseline (401.354 us; speedup 1.0000x reference)
//
#include <hip/hip_runtime.h>
#include <type_traits>

// ---------- types ----------
typedef short s8v   __attribute__((ext_vector_type(8)));   // 8 x bf16 bits
typedef short s4v   __attribute__((ext_vector_type(4)));
typedef float f32x4 __attribute__((ext_vector_type(4)));

__device__ __forceinline__ unsigned short f2bf(float f) {
    unsigned int u = __builtin_bit_cast(unsigned int, f);
    u += 0x7FFF + ((u >> 16) & 1);          // round-to-nearest-even
    return (unsigned short)(u >> 16);
}
__device__ __forceinline__ float bf2f(unsigned short b) {
    unsigned int u = ((unsigned int)b) << 16;
    return __builtin_bit_cast(float, u);
}

__device__ __forceinline__ void gload16(const void* g, void* l) {
    __builtin_amdgcn_global_load_lds(
        (const __attribute__((address_space(1))) void*)g,
        (__attribute__((address_space(3))) void*)l, 16, 0, 0);
}

// ---------- x -> bf16 (vectorized) ----------
__global__ void conv_bf16(const float* __restrict__ src, unsigned short* __restrict__ dst, int n8) {
    int i = blockIdx.x * blockDim.x + threadIdx.x;
    if (i >= n8) return;
    const f32x4* s4 = (const f32x4*)src;
    f32x4 a = s4[2 * i], b = s4[2 * i + 1];
    s8v o;
    o[0] = (short)f2bf(a[0]); o[1] = (short)f2bf(a[1]);
    o[2] = (short)f2bf(a[2]); o[3] = (short)f2bf(a[3]);
    o[4] = (short)f2bf(b[0]); o[5] = (short)f2bf(b[1]);
    o[6] = (short)f2bf(b[2]); o[7] = (short)f2bf(b[3]);
    *(s8v*)(dst + (size_t)i * 8) = o;
}

// ---------- W (KxN f32) -> W^T (NxK bf16) ----------
__global__ void transpose_conv(const float* __restrict__ src, unsigned short* __restrict__ dst,
                               int K, int N) {
    __shared__ float tile[32][33];
    int n0 = blockIdx.x * 32, k0 = blockIdx.y * 32;
    int tx = threadIdx.x, ty = threadIdx.y;     // 32 x 8
#pragma unroll
    for (int r = 0; r < 4; ++r)
        tile[ty + r * 8][tx] = src[(size_t)(k0 + ty + r * 8) * N + n0 + tx];
    __syncthreads();
#pragma unroll
    for (int r = 0; r < 4; ++r)
        dst[(size_t)(n0 + ty + r * 8) * K + k0 + tx] = f2bf(tile[tx][ty + r * 8]);
}

// ---------- GEMM: C(MxN) = A(MxK,bf16) * B^T(NxK,bf16), m97 structure ----------
template <typename CT>
__global__ __launch_bounds__(256)
void gemm_bt(const unsigned short* __restrict__ A, const unsigned short* __restrict__ BT,
             CT* __restrict__ C, int M, int N, int K, int ldc) {
    __shared__ unsigned short As[128 * 32];
    __shared__ unsigned short Bs[128 * 32];
    const int tid = threadIdx.x;
    const int wid = tid >> 6, lane = tid & 63;
    const int lr = lane & 15, lg = lane >> 4;
    const int brow = blockIdx.y * 128, bcol = blockIdx.x * 128;
    const int wr = wid >> 1, wc = wid & 1;      // 2x2 waves, 64x64 each
    f32x4 acc[4][4] = {};

    for (int kt = 0; kt < K; kt += 32) {
#pragma unroll
        for (int i = 0; i < 2; ++i) {
            int f = i * 256 + tid;              // unit of 8 elems
            int row = f >> 2;
            int col8 = (f & 3) << 3;
            gload16(A + (size_t)(brow + row) * K + kt + col8,
                    As + (size_t)(i * 256 + wid * 64) * 8);
            gload16(BT + (size_t)(bcol + row) * K + kt + col8,
                    Bs + (size_t)(i * 256 + wid * 64) * 8);
        }
        __syncthreads();
        s8v a[4], b[4];
#pragma unroll
        for (int m = 0; m < 4; ++m)
            a[m] = *(const s8v*)(As + (size_t)(wr * 64 + m * 16 + lr) * 32 + lg * 8);
#pragma unroll
        for (int n = 0; n < 4; ++n)
            b[n] = *(const s8v*)(Bs + (size_t)(wc * 64 + n * 16 + lr) * 32 + lg * 8);
#pragma unroll
        for (int m = 0; m < 4; ++m)
#pragma unroll
            for (int n = 0; n < 4; ++n)
                acc[m][n] = __builtin_amdgcn_mfma_f32_16x16x32_bf16(a[m], b[n], acc[m][n], 0, 0, 0);
        __syncthreads();
    }
    // epilogue: C/D layout col = lane&15, row = (lane>>4)*4 + j
#pragma unroll
    for (int m = 0; m < 4; ++m)
#pragma unroll
        for (int n = 0; n < 4; ++n)
#pragma unroll
            for (int j = 0; j < 4; ++j) {
                int r = brow + wr * 64 + m * 16 + lg * 4 + j;
                int c = bcol + wc * 64 + n * 16 + lr;
                float v = acc[m][n][j];
                if constexpr (std::is_same<CT, float>::value)
                    C[(size_t)r * ldc + c] = v;
                else
                    C[(size_t)r * ldc + c] = f2bf(v);
            }
}

// ---------- RoPE in-place on qkv buffer [4096][3072]; q: cols 0..2047, k: 2048..2559 ----------
__global__ void rope_kernel(unsigned short* __restrict__ qkv,
                            const float* __restrict__ fc, const float* __restrict__ fs) {
    int idx = blockIdx.x * blockDim.x + threadIdx.x;   // 4096 * 20 * 16
    if (idx >= 4096 * 20 * 16) return;
    int grp = idx & 15;
    int hh = (idx >> 4) % 20;
    int row = idx / (16 * 20);
    int s = row & 2047;
    int col0 = (hh < 16 ? hh * 128 : 2048 + (hh - 16) * 128) + grp * 8;
    unsigned short* p = qkv + (size_t)row * 3072 + col0;
    s8v v = *(const s8v*)p;
    const float* cc = fc + (size_t)s * 64 + grp * 4;
    const float* ss = fs + (size_t)s * 64 + grp * 4;
#pragma unroll
    for (int j = 0; j < 4; ++j) {
        float xe = bf2f((unsigned short)v[2 * j]);
        float xo = bf2f((unsigned short)v[2 * j + 1]);
        float c = cc[j], sn = ss[j];
        v[2 * j]     = (short)f2bf(xe * c - xo * sn);
        v[2 * j + 1] = (short)f2bf(xe * sn + xo * c);
    }
    *(s8v*)p = v;
}

// ---------- Flash attention, GQA, causal ----------
// grid.x = B*H (32): b = x>>4, h = x&15, kvh = h>>2 ; grid.y = q-tile of 64 (32)
// block = 256 threads (4 waves); wave w handles q rows [q0 + w*16, +16)
__global__ __launch_bounds__(256)
void attn_kernel(const unsigned short* __restrict__ qkv, unsigned short* __restrict__ out) {
    constexpr int S = 2048, HD = 128;
    __shared__ unsigned short Ks[32 * 128];   // XOR-swizzled, rows = key
    __shared__ unsigned short Vt[128 * 32];   // V^T: [d][key]
    __shared__ unsigned short Ps[4][16 * 32]; // per-wave P tile
    const int tid = threadIdx.x, lane = tid & 63, wid = tid >> 6;
    const int lr = lane & 15, lg = lane >> 4;
    const int b = blockIdx.x >> 4, h = blockIdx.x & 15;
    const int kvh = h >> 2;
    const int q0 = blockIdx.y * 64;
    const int qw = q0 + wid * 16;
    const size_t rs = 3072;
    const unsigned short* Qbase = qkv + (size_t)(b * S) * rs + h * HD;
    const unsigned short* Kbase = qkv + (size_t)(b * S) * rs + 2048 + kvh * HD;
    const unsigned short* Vbase = Kbase + 512;
    const float rscale = 0.08838834764831845f;  // 1/sqrt(128)

    // Q fragments (B operand of swapped QK^T): col=q=lr, k=d contiguous
    s8v qf[4];
#pragma unroll
    for (int kk = 0; kk < 4; ++kk)
        qf[kk] = *(const s8v*)(Qbase + (size_t)(qw + lr) * rs + kk * 32 + lg * 8);

    f32x4 acc[8] = {};
    float m_run = -1e30f, l_run = 0.f;
    const int nt = (q0 + 64 + 31) / 32;

    for (int t = 0; t < nt; ++t) {
        const int kb = t * 32;
        // ---- stage K (swizzled) and V^T ----
#pragma unroll
        for (int i = 0; i < 2; ++i) {
            int f = i * 256 + tid;
            int key = f >> 4, dc = (f & 15) << 3;
            s8v kv8 = *(const s8v*)(Kbase + (size_t)(kb + key) * rs + dc);
            int byte = key * 256 + dc * 2;
            byte ^= ((key & 7) << 4);
            *(s8v*)((char*)Ks + byte) = kv8;
            s8v vv = *(const s8v*)(Vbase + (size_t)(kb + key) * rs + dc);
#pragma unroll
            for (int j = 0; j < 8; ++j)
                Vt[(size_t)(dc + j) * 32 + key] = (unsigned short)vv[j];
        }
        __syncthreads();

        // ---- QK^T (swapped: scoresT[key][q]) ----
        float sv[8];
#pragma unroll
        for (int kt = 0; kt < 2; ++kt) {
            f32x4 sacc = {};
#pragma unroll
            for (int kk = 0; kk < 4; ++kk) {
                int key = kt * 16 + lr;
                int byte = key * 256 + (kk * 32 + lg * 8) * 2;
                byte ^= ((key & 7) << 4);
                s8v af = *(const s8v*)((const char*)Ks + byte);
                sacc = __builtin_amdgcn_mfma_f32_16x16x32_bf16(af, qf[kk], sacc, 0, 0, 0);
            }
#pragma unroll
            for (int j = 0; j < 4; ++j) {
                int key = kb + kt * 16 + lg * 4 + j;
                int qq = qw + lr;
                float s = sacc[j] * rscale;
                sv[kt * 4 + j] = (key <= qq) ? s : -1e30f;
            }
        }
        // ---- online softmax (per q = lr, keys spread over lg + regs) ----
        float mx = sv[0];
#pragma unroll
        for (int i = 1; i < 8; ++i) mx = fmaxf(mx, sv[i]);
        mx = fmaxf(mx, __shfl_xor(mx, 16));
        mx = fmaxf(mx, __shfl_xor(mx, 32));
        float m_new = fmaxf(m_run, mx);
        float alpha = __expf(m_run - m_new);
        float ps = 0.f;
        unsigned short pb[8];
#pragma unroll
        for (int i = 0; i < 8; ++i) {
            float p = __expf(sv[i] - m_new);
            ps += p;
            pb[i] = f2bf(p);
        }
        ps += __shfl_xor(ps, 16);
        ps += __shfl_xor(ps, 32);
        l_run = l_run * alpha + ps;
        m_run = m_new;
        // rescale accumulator; acc rows are q = lg*4+j -> fetch alpha from lane (lg*4+j)
        float al[4];
#pragma unroll
        for (int j = 0; j < 4; ++j) al[j] = __shfl(alpha, (lg << 2) + j);
#pragma unroll
        for (int n = 0; n < 8; ++n)
#pragma unroll
            for (int j = 0; j < 4; ++j) acc[n][j] *= al[j];
        // ---- write P tile (row q = lr, keys kt*16 + lg*4 + 0..3) ----
        unsigned short* Pw = &Ps[wid][0];
        s4v w0; w0[0] = (short)pb[0]; w0[1] = (short)pb[1]; w0[2] = (short)pb[2]; w0[3] = (short)pb[3];
        s4v w1; w1[0] = (short)pb[4]; w1[1] = (short)pb[5]; w1[2] = (short)pb[6]; w1[3] = (short)pb[7];
        *(s4v*)(Pw + lr * 32 + lg * 4) = w0;
        *(s4v*)(Pw + lr * 32 + 16 + lg * 4) = w1;
        // ---- PV: out[q][d] += P(16x32) * V(32x128) ----
        s8v pf = *(const s8v*)(Pw + lr * 32 + lg * 8);
#pragma unroll
        for (int n = 0; n < 8; ++n) {
            s8v vf = *(const s8v*)(Vt + (size_t)(n * 16 + lr) * 32 + lg * 8);
            acc[n] = __builtin_amdgcn_mfma_f32_16x16x32_bf16(pf, vf, acc[n], 0, 0, 0);
        }
        __syncthreads();
    }
    // ---- normalize and store (acc row q = lg*4+j, col d = n*16+lr) ----
    float li[4];
#pragma unroll
    for (int j = 0; j < 4; ++j) li[j] = 1.f / __shfl(l_run, (lg << 2) + j);
#pragma unroll
    for (int n = 0; n < 8; ++n)
#pragma unroll
        for (int j = 0; j < 4; ++j) {
            int r = b * S + qw + lg * 4 + j;
            int c = h * HD + n * 16 + lr;
            out[(size_t)r * 2048 + c] = f2bf(acc[n][j] * li[j]);
        }
}

// ---------- launch ----------
extern "C" void kernel_launch(void* const* d_in, const int* in_sizes, int n_in,
                              void* d_out, int out_size, void* d_ws, size_t ws_size,
                              hipStream_t stream) {
    const float* x  = (const float*)d_in[0];
    const float* fc = (const float*)d_in[1];
    const float* fs = (const float*)d_in[2];
    const float* wq = (const float*)d_in[4];
    const float* wk = (const float*)d_in[5];
    const float* wv = (const float*)d_in[6];
    const float* wo = (const float*)d_in[7];
    float* out = (float*)d_out;

    char* ws = (char*)d_ws;
    unsigned short* xb    = (unsigned short*)ws;                               // 16 MB (reused as attn out)
    unsigned short* wqkvT = (unsigned short*)(ws + 16777216);                  // 12 MB
    unsigned short* woT   = (unsigned short*)(ws + 16777216 + 12582912);       // 8 MB
    unsigned short* qkvb  = (unsigned short*)(ws + 16777216 + 12582912 + 8388608); // 24 MB
    unsigned short* attnb = xb;

    conv_bf16<<<4096, 256, 0, stream>>>(x, xb, 1048576);
    dim3 tb(32, 8);
    transpose_conv<<<dim3(64, 64), tb, 0, stream>>>(wq, wqkvT, 2048, 2048);
    transpose_conv<<<dim3(16, 64), tb, 0, stream>>>(wk, wqkvT + (size_t)2048 * 2048, 2048, 512);
    transpose_conv<<<dim3(16, 64), tb, 0, stream>>>(wv, wqkvT + (size_t)2560 * 2048, 2048, 512);
    transpose_conv<<<dim3(64, 64), tb, 0, stream>>>(wo, woT, 2048, 2048);
    gemm_bt<unsigned short><<<dim3(24, 32), 256, 0, stream>>>(xb, wqkvT, qkvb, 4096, 3072, 2048, 3072);
    rope_kernel<<<5120, 256, 0, stream>>>(qkvb, fc, fs);
    attn_kernel<<<dim3(32, 32), 256, 0, stream>>>(qkvb, attnb);
    gemm_bt<float><<<dim3(16, 32), 256, 0, stream>>>(attnb, woT, out, 4096, 2048, 2048, 2048);
}

// Round 4
// 325.512 us; speedup vs baseline: 1.2330x; 1.2330x over previous
//
#include <hip/hip_runtime.h>
#include <type_traits>

// ---------- types ----------
typedef short s8v   __attribute__((ext_vector_type(8)));   // 8 x bf16 bits
typedef float f32x4 __attribute__((ext_vector_type(4)));
typedef unsigned int u32x4 __attribute__((ext_vector_type(4)));

__device__ __forceinline__ unsigned short f2bf(float f) {
    unsigned int u = __builtin_bit_cast(unsigned int, f);
    u += 0x7FFF + ((u >> 16) & 1);          // round-to-nearest-even
    return (unsigned short)(u >> 16);
}
__device__ __forceinline__ float bf2f(unsigned short b) {
    unsigned int u = ((unsigned int)b) << 16;
    return __builtin_bit_cast(float, u);
}

__device__ __forceinline__ void gload16(const void* g, void* l) {
    __builtin_amdgcn_global_load_lds(
        (const __attribute__((address_space(1))) void*)g,
        (__attribute__((address_space(3))) void*)l, 16, 0, 0);
}

// ---------- x -> bf16 (vectorized) ----------
__global__ void conv_bf16(const float* __restrict__ src, unsigned short* __restrict__ dst, int n8) {
    int i = blockIdx.x * blockDim.x + threadIdx.x;
    if (i >= n8) return;
    const f32x4* s4 = (const f32x4*)src;
    f32x4 a = s4[2 * i], b = s4[2 * i + 1];
    s8v o;
    o[0] = (short)f2bf(a[0]); o[1] = (short)f2bf(a[1]);
    o[2] = (short)f2bf(a[2]); o[3] = (short)f2bf(a[3]);
    o[4] = (short)f2bf(b[0]); o[5] = (short)f2bf(b[1]);
    o[6] = (short)f2bf(b[2]); o[7] = (short)f2bf(b[3]);
    *(s8v*)(dst + (size_t)i * 8) = o;
}

// ---------- W (KxN f32) -> W^T (NxK bf16) ----------
__global__ void transpose_conv(const float* __restrict__ src, unsigned short* __restrict__ dst,
                               int K, int N) {
    __shared__ float tile[32][33];
    int n0 = blockIdx.x * 32, k0 = blockIdx.y * 32;
    int tx = threadIdx.x, ty = threadIdx.y;     // 32 x 8
#pragma unroll
    for (int r = 0; r < 4; ++r)
        tile[ty + r * 8][tx] = src[(size_t)(k0 + ty + r * 8) * N + n0 + tx];
    __syncthreads();
#pragma unroll
    for (int r = 0; r < 4; ++r)
        dst[(size_t)(n0 + ty + r * 8) * K + k0 + tx] = f2bf(tile[tx][ty + r * 8]);
}

// ---------- V (cols 2560..3071 of qkv) -> V^T [b][kvh][128][2048] bf16 ----------
__global__ void vtrans(const unsigned short* __restrict__ qkv, unsigned short* __restrict__ vt) {
    __shared__ unsigned short t[32][33];
    int s0 = blockIdx.x * 32;          // global row 0..4095
    int c0 = blockIdx.y * 32;          // v-col 0..511
    int tx = threadIdx.x, ty = threadIdx.y;   // 32 x 8
#pragma unroll
    for (int r = 0; r < 4; ++r)
        t[ty + r * 8][tx] = qkv[(size_t)(s0 + ty + r * 8) * 3072 + 2560 + c0 + tx];
    __syncthreads();
    int b = s0 >> 11, s = s0 & 2047;
    size_t dbase = (size_t)(b * 4 + (c0 >> 7)) * 128 + (c0 & 127);
#pragma unroll
    for (int r = 0; r < 4; ++r)
        vt[(dbase + ty + r * 8) * 2048 + s + tx] = t[tx][ty + r * 8];
}

// ---------- GEMM: C(MxN) = A(MxK,bf16) * B^T(NxK,bf16), m97 structure ----------
template <typename CT>
__global__ __launch_bounds__(256)
void gemm_bt(const unsigned short* __restrict__ A, const unsigned short* __restrict__ BT,
             CT* __restrict__ C, int M, int N, int K, int ldc) {
    __shared__ unsigned short As[128 * 32];
    __shared__ unsigned short Bs[128 * 32];
    const int tid = threadIdx.x;
    const int wid = tid >> 6, lane = tid & 63;
    const int lr = lane & 15, lg = lane >> 4;
    const int brow = blockIdx.y * 128, bcol = blockIdx.x * 128;
    const int wr = wid >> 1, wc = wid & 1;      // 2x2 waves, 64x64 each
    f32x4 acc[4][4] = {};

    for (int kt = 0; kt < K; kt += 32) {
#pragma unroll
        for (int i = 0; i < 2; ++i) {
            int f = i * 256 + tid;              // unit of 8 elems
            int row = f >> 2;
            int col8 = (f & 3) << 3;
            gload16(A + (size_t)(brow + row) * K + kt + col8,
                    As + (size_t)(i * 256 + wid * 64) * 8);
            gload16(BT + (size_t)(bcol + row) * K + kt + col8,
                    Bs + (size_t)(i * 256 + wid * 64) * 8);
        }
        __syncthreads();
        s8v a[4], b[4];
#pragma unroll
        for (int m = 0; m < 4; ++m)
            a[m] = *(const s8v*)(As + (size_t)(wr * 64 + m * 16 + lr) * 32 + lg * 8);
#pragma unroll
        for (int n = 0; n < 4; ++n)
            b[n] = *(const s8v*)(Bs + (size_t)(wc * 64 + n * 16 + lr) * 32 + lg * 8);
#pragma unroll
        for (int m = 0; m < 4; ++m)
#pragma unroll
            for (int n = 0; n < 4; ++n)
                acc[m][n] = __builtin_amdgcn_mfma_f32_16x16x32_bf16(a[m], b[n], acc[m][n], 0, 0, 0);
        __syncthreads();
    }
#pragma unroll
    for (int m = 0; m < 4; ++m)
#pragma unroll
        for (int n = 0; n < 4; ++n)
#pragma unroll
            for (int j = 0; j < 4; ++j) {
                int r = brow + wr * 64 + m * 16 + lg * 4 + j;
                int c = bcol + wc * 64 + n * 16 + lr;
                float v = acc[m][n][j];
                if constexpr (std::is_same<CT, float>::value)
                    C[(size_t)r * ldc + c] = v;
                else
                    C[(size_t)r * ldc + c] = f2bf(v);
            }
}

// ---------- RoPE in-place on qkv buffer [4096][3072]; q: cols 0..2047, k: 2048..2559 ----------
__global__ void rope_kernel(unsigned short* __restrict__ qkv,
                            const float* __restrict__ fc, const float* __restrict__ fs) {
    int idx = blockIdx.x * blockDim.x + threadIdx.x;   // 4096 * 20 * 16
    if (idx >= 4096 * 20 * 16) return;
    int grp = idx & 15;
    int hh = (idx >> 4) % 20;
    int row = idx / (16 * 20);
    int s = row & 2047;
    int col0 = (hh < 16 ? hh * 128 : 2048 + (hh - 16) * 128) + grp * 8;
    unsigned short* p = qkv + (size_t)row * 3072 + col0;
    s8v v = *(const s8v*)p;
    const float* cc = fc + (size_t)s * 64 + grp * 4;
    const float* ss = fs + (size_t)s * 64 + grp * 4;
#pragma unroll
    for (int j = 0; j < 4; ++j) {
        float xe = bf2f((unsigned short)v[2 * j]);
        float xo = bf2f((unsigned short)v[2 * j + 1]);
        float c = cc[j], sn = ss[j];
        v[2 * j]     = (short)f2bf(xe * c - xo * sn);
        v[2 * j + 1] = (short)f2bf(xe * sn + xo * c);
    }
    *(s8v*)p = v;
}

// ---------- Flash attention, GQA, causal — LDS conflict-free, in-register P ----------
// 512 blocks (1D, XCD-chunk-swizzled), 256 threads (4 waves).
// Each block: 128 q rows; wave w owns rows [q0+32w, +32) as two 16-row MFMA groups.
// KV tile = 64 keys, double-buffered LDS; K and V^T staged via global_load_lds with
// pre-swizzled global source (XOR unit^(row&7)) -> conflict-free ds_read_b128.
__global__ __launch_bounds__(256)
void attn_kernel(const unsigned short* __restrict__ qkv,
                 const unsigned short* __restrict__ vtg,
                 unsigned short* __restrict__ out) {
    constexpr int S = 2048;
    __shared__ unsigned short Ks[2][64 * 128];   // [key][d], units-of-8 XOR-swizzled by key&7
    __shared__ unsigned short Vs[2][128 * 64];   // [d][key], units-of-8 XOR-swizzled by d&7
    const int tid = threadIdx.x, lane = tid & 63, wid = tid >> 6;
    const int lr = lane & 15, lg = lane >> 4;
    const int lsw = lr & 7;
    // bijective XCD chunk swizzle: 512 blocks, 64 per XCD -> one (b,kvh) per 2 XCDs
    int swz = (blockIdx.x & 7) * 64 + (blockIdx.x >> 3);
    const int bh = swz >> 4, qb = swz & 15;
    const int b = bh >> 4, h = bh & 15, kvh = h >> 2;
    const int q0 = qb * 128;
    const int qw = q0 + wid * 32;
    const size_t rs = 3072;
    const unsigned short* Qbase = qkv + (size_t)(b * S) * rs + h * 128;
    const unsigned short* Kbase = qkv + (size_t)(b * S) * rs + 2048 + kvh * 128;
    const unsigned short* Vtg  = vtg + (size_t)(b * 4 + kvh) * 128 * S;
    const float rscale = 0.08838834764831845f;  // 1/sqrt(128)

    // Q fragments (B operand of swapped QK^T): col=q, k=d contiguous
    s8v qf[2][4];
#pragma unroll
    for (int m = 0; m < 2; ++m)
#pragma unroll
        for (int kk = 0; kk < 4; ++kk)
            qf[m][kk] = *(const s8v*)(Qbase + (size_t)(qw + m * 16 + lr) * rs + kk * 32 + lg * 8);

    f32x4 acc[2][8] = {};
    float m_run[2] = {-1e30f, -1e30f};
    float l_run[2] = {0.f, 0.f};
    const int nt = qb * 2 + 2;

    auto stage = [&](int t, int bufi) {
        const int kb = t * 64;
#pragma unroll
        for (int i = 0; i < 4; ++i) {           // K tile: 1024 chunks of 16B
            int c = i * 256 + tid;
            int key = c >> 4, d8 = c & 15;
            gload16(Kbase + (size_t)(kb + key) * rs + ((d8 ^ (key & 7)) << 3),
                    &Ks[bufi][(size_t)(i * 256 + wid * 64) * 8]);
        }
#pragma unroll
        for (int i = 0; i < 4; ++i) {           // V^T tile
            int c = i * 256 + tid;
            int d = c >> 3, k8 = c & 7;
            gload16(Vtg + (size_t)d * S + kb + ((k8 ^ (d & 7)) << 3),
                    &Vs[bufi][(size_t)(i * 256 + wid * 64) * 8]);
        }
    };

    int cur = 0;
    stage(0, 0);
    __syncthreads();

    for (int t = 0; t < nt; ++t) {
        if (t + 1 < nt) stage(t + 1, cur ^ 1);
        const int kb = t * 64;
        if (kb <= qw + 31) {                    // wave-uniform skip of fully-masked tiles
            const char* Kb = (const char*)&Ks[cur][0];
            const char* Vb = (const char*)&Vs[cur][0];
            // ---- QK^T (swapped): D[key][q], both m groups share K fragments ----
            float p[2][16];
#pragma unroll
            for (int kt = 0; kt < 4; ++kt) {
                int key = kt * 16 + lr;
                s8v a[4];
#pragma unroll
                for (int kk = 0; kk < 4; ++kk)
                    a[kk] = *(const s8v*)(Kb + key * 256 + (((kk * 4 + lg) ^ lsw) << 4));
                __builtin_amdgcn_s_setprio(1);
#pragma unroll
                for (int m = 0; m < 2; ++m) {
                    f32x4 sacc = {};
#pragma unroll
                    for (int kk = 0; kk < 4; ++kk)
                        sacc = __builtin_amdgcn_mfma_f32_16x16x32_bf16(a[kk], qf[m][kk], sacc, 0, 0, 0);
                    int qg = qw + m * 16 + lr;
#pragma unroll
                    for (int j = 0; j < 4; ++j) {
                        int keyg = kb + kt * 16 + lg * 4 + j;
                        float s = sacc[j] * rscale;
                        p[m][kt * 4 + j] = (keyg <= qg) ? s : -1e30f;
                    }
                }
                __builtin_amdgcn_s_setprio(0);
            }
            // ---- online softmax + in-register P redistribute ----
            unsigned int paw[2][2][4];
#pragma unroll
            for (int m = 0; m < 2; ++m) {
                float mx = p[m][0];
#pragma unroll
                for (int i = 1; i < 16; ++i) mx = fmaxf(mx, p[m][i]);
                mx = fmaxf(mx, __shfl_xor(mx, 16));
                mx = fmaxf(mx, __shfl_xor(mx, 32));
                float mn = fmaxf(m_run[m], mx);
                float alpha = __expf(m_run[m] - mn);
                float ps = 0.f;
                unsigned short pb[16];
#pragma unroll
                for (int i = 0; i < 16; ++i) {
                    float e = __expf(p[m][i] - mn);
                    ps += e;
                    pb[i] = f2bf(e);
                }
                ps += __shfl_xor(ps, 16);
                ps += __shfl_xor(ps, 32);
                l_run[m] = l_run[m] * alpha + ps;
                m_run[m] = mn;
                unsigned int pk[8];
#pragma unroll
                for (int kt = 0; kt < 4; ++kt)
#pragma unroll
                    for (int w2 = 0; w2 < 2; ++w2)
                        pk[kt * 2 + w2] = (unsigned)pb[kt * 4 + w2 * 2] |
                                          ((unsigned)pb[kt * 4 + w2 * 2 + 1] << 16);
                // redistribute for PV A-fragment:
                //   target word (k2,w) at lane (lg,lr) = keys (k2*32+lg*8+2w, +1), q=lr
                //   source word index = 4*k2 + 2*(lg>>1) + (w&1)   [depends on TARGET lg]
                //   source lane       = (2*(lg&1) + (w>>1))*16 + lr
                // __shfl evaluates its operand on the SOURCE lane, so fetch BOTH
                // candidate words and select on the target side by lg>>1.
#pragma unroll
                for (int k2 = 0; k2 < 2; ++k2)
#pragma unroll
                    for (int w = 0; w < 4; ++w) {
                        int src = (((lg & 1) * 2 + (w >> 1)) << 4) + lr;
                        unsigned int lo = (unsigned)__shfl((int)pk[k2 * 4 + (w & 1)], src);
                        unsigned int hi = (unsigned)__shfl((int)pk[k2 * 4 + 2 + (w & 1)], src);
                        paw[m][k2][w] = (lg & 2) ? hi : lo;
                    }
                // rescale accumulator: row q&15 = lg*4+j
                float al[4];
#pragma unroll
                for (int j = 0; j < 4; ++j) al[j] = __shfl(alpha, lg * 4 + j);
#pragma unroll
                for (int n = 0; n < 8; ++n)
#pragma unroll
                    for (int j = 0; j < 4; ++j) acc[m][n][j] *= al[j];
            }
            // ---- PV: acc[q][d] += P[32x64] * V[64x128], V fragments shared by m ----
#pragma unroll
            for (int k2 = 0; k2 < 2; ++k2) {
                s8v pa[2];
#pragma unroll
                for (int m = 0; m < 2; ++m) {
                    u32x4 wv;
                    wv[0] = paw[m][k2][0]; wv[1] = paw[m][k2][1];
                    wv[2] = paw[m][k2][2]; wv[3] = paw[m][k2][3];
                    pa[m] = __builtin_bit_cast(s8v, wv);
                }
                __builtin_amdgcn_s_setprio(1);
#pragma unroll
                for (int n = 0; n < 8; ++n) {
                    int d = n * 16 + lr;
                    const s8v vf = *(const s8v*)(Vb + d * 128 + (((k2 * 4 + lg) ^ lsw) << 4));
#pragma unroll
                    for (int m = 0; m < 2; ++m)
                        acc[m][n] = __builtin_amdgcn_mfma_f32_16x16x32_bf16(pa[m], vf, acc[m][n], 0, 0, 0);
                }
                __builtin_amdgcn_s_setprio(0);
            }
        }
        __syncthreads();
        cur ^= 1;
    }
    // ---- normalize and store (row q = qw + m*16 + lg*4+j, col d = n*16+lr) ----
    float li[2][4];
#pragma unroll
    for (int m = 0; m < 2; ++m) {
        float inv = 1.f / l_run[m];
#pragma unroll
        for (int j = 0; j < 4; ++j) li[m][j] = __shfl(inv, lg * 4 + j);
    }
#pragma unroll
    for (int m = 0; m < 2; ++m)
#pragma unroll
        for (int n = 0; n < 8; ++n)
#pragma unroll
            for (int j = 0; j < 4; ++j) {
                int q = qw + m * 16 + lg * 4 + j;
                out[(size_t)(b * S + q) * 2048 + h * 128 + n * 16 + lr] =
                    f2bf(acc[m][n][j] * li[m][j]);
            }
}

// ---------- launch ----------
extern "C" void kernel_launch(void* const* d_in, const int* in_sizes, int n_in,
                              void* d_out, int out_size, void* d_ws, size_t ws_size,
                              hipStream_t stream) {
    const float* x  = (const float*)d_in[0];
    const float* fc = (const float*)d_in[1];
    const float* fs = (const float*)d_in[2];
    const float* wq = (const float*)d_in[4];
    const float* wk = (const float*)d_in[5];
    const float* wv = (const float*)d_in[6];
    const float* wo = (const float*)d_in[7];
    float* out = (float*)d_out;

    char* ws = (char*)d_ws;
    unsigned short* xb    = (unsigned short*)ws;                               // 16 MB (reused as attn out)
    unsigned short* wqkvT = (unsigned short*)(ws + 16777216);                  // 12 MB (reused as V^T)
    unsigned short* woT   = (unsigned short*)(ws + 16777216 + 12582912);       // 8 MB
    unsigned short* qkvb  = (unsigned short*)(ws + 16777216 + 12582912 + 8388608); // 24 MB
    unsigned short* attnb = xb;
    unsigned short* vtb   = wqkvT;      // V^T [2][4][128][2048] = 4 MB, lives after gemm1

    conv_bf16<<<4096, 256, 0, stream>>>(x, xb, 1048576);
    dim3 tb(32, 8);
    transpose_conv<<<dim3(64, 64), tb, 0, stream>>>(wq, wqkvT, 2048, 2048);
    transpose_conv<<<dim3(16, 64), tb, 0, stream>>>(wk, wqkvT + (size_t)2048 * 2048, 2048, 512);
    transpose_conv<<<dim3(16, 64), tb, 0, stream>>>(wv, wqkvT + (size_t)2560 * 2048, 2048, 512);
    transpose_conv<<<dim3(64, 64), tb, 0, stream>>>(wo, woT, 2048, 2048);
    gemm_bt<unsigned short><<<dim3(24, 32), 256, 0, stream>>>(xb, wqkvT, qkvb, 4096, 3072, 2048, 3072);
    rope_kernel<<<5120, 256, 0, stream>>>(qkvb, fc, fs);
    vtrans<<<dim3(128, 16), tb, 0, stream>>>(qkvb, vtb);
    attn_kernel<<<512, 256, 0, stream>>>(qkvb, vtb, attnb);
    gemm_bt<float><<<dim3(16, 32), 256, 0, stream>>>(attnb, woT, out, 4096, 2048, 2048, 2048);
}

// Round 5
// 294.966 us; speedup vs baseline: 1.3607x; 1.1036x over previous
//
#include <hip/hip_runtime.h>
#include <type_traits>

// ---------- types ----------
typedef short s8v   __attribute__((ext_vector_type(8)));   // 8 x bf16 bits
typedef float f32x4 __attribute__((ext_vector_type(4)));
typedef float f32x16 __attribute__((ext_vector_type(16)));
typedef unsigned int u32x2 __attribute__((ext_vector_type(2)));
typedef unsigned int u32x4 __attribute__((ext_vector_type(4)));

__device__ __forceinline__ unsigned short f2bf(float f) {
    unsigned int u = __builtin_bit_cast(unsigned int, f);
    u += 0x7FFF + ((u >> 16) & 1);          // round-to-nearest-even
    return (unsigned short)(u >> 16);
}
__device__ __forceinline__ float bf2f(unsigned short b) {
    unsigned int u = ((unsigned int)b) << 16;
    return __builtin_bit_cast(float, u);
}
__device__ __forceinline__ unsigned int cvtpk(float lo, float hi) {
    unsigned int w;
    asm("v_cvt_pk_bf16_f32 %0, %1, %2" : "=v"(w) : "v"(lo), "v"(hi));
    return w;
}

__device__ __forceinline__ void gload16(const void* g, void* l) {
    __builtin_amdgcn_global_load_lds(
        (const __attribute__((address_space(1))) void*)g,
        (__attribute__((address_space(3))) void*)l, 16, 0, 0);
}

// ---------- x -> bf16 (vectorized) ----------
__global__ void conv_bf16(const float* __restrict__ src, unsigned short* __restrict__ dst, int n8) {
    int i = blockIdx.x * blockDim.x + threadIdx.x;
    if (i >= n8) return;
    const f32x4* s4 = (const f32x4*)src;
    f32x4 a = s4[2 * i], b = s4[2 * i + 1];
    s8v o;
    o[0] = (short)f2bf(a[0]); o[1] = (short)f2bf(a[1]);
    o[2] = (short)f2bf(a[2]); o[3] = (short)f2bf(a[3]);
    o[4] = (short)f2bf(b[0]); o[5] = (short)f2bf(b[1]);
    o[6] = (short)f2bf(b[2]); o[7] = (short)f2bf(b[3]);
    *(s8v*)(dst + (size_t)i * 8) = o;
}

// ---------- W (KxN f32) -> W^T (NxK bf16) ----------
__global__ void transpose_conv(const float* __restrict__ src, unsigned short* __restrict__ dst,
                               int K, int N) {
    __shared__ float tile[32][33];
    int n0 = blockIdx.x * 32, k0 = blockIdx.y * 32;
    int tx = threadIdx.x, ty = threadIdx.y;     // 32 x 8
#pragma unroll
    for (int r = 0; r < 4; ++r)
        tile[ty + r * 8][tx] = src[(size_t)(k0 + ty + r * 8) * N + n0 + tx];
    __syncthreads();
#pragma unroll
    for (int r = 0; r < 4; ++r)
        dst[(size_t)(n0 + ty + r * 8) * K + k0 + tx] = f2bf(tile[tx][ty + r * 8]);
}

// ---------- V (cols 2560..3071 of qkv) -> V^T [b][kvh][128][2048] bf16 ----------
__global__ void vtrans(const unsigned short* __restrict__ qkv, unsigned short* __restrict__ vt) {
    __shared__ unsigned short t[32][33];
    int s0 = blockIdx.x * 32;          // global row 0..4095
    int c0 = blockIdx.y * 32;          // v-col 0..511
    int tx = threadIdx.x, ty = threadIdx.y;   // 32 x 8
#pragma unroll
    for (int r = 0; r < 4; ++r)
        t[ty + r * 8][tx] = qkv[(size_t)(s0 + ty + r * 8) * 3072 + 2560 + c0 + tx];
    __syncthreads();
    int b = s0 >> 11, s = s0 & 2047;
    size_t dbase = (size_t)(b * 4 + (c0 >> 7)) * 128 + (c0 & 127);
#pragma unroll
    for (int r = 0; r < 4; ++r)
        vt[(dbase + ty + r * 8) * 2048 + s + tx] = t[tx][ty + r * 8];
}

// ---------- GEMM: C(MxN) = A(MxK,bf16) * B^T(NxK,bf16), m97 structure ----------
template <typename CT>
__global__ __launch_bounds__(256)
void gemm_bt(const unsigned short* __restrict__ A, const unsigned short* __restrict__ BT,
             CT* __restrict__ C, int M, int N, int K, int ldc) {
    __shared__ unsigned short As[128 * 32];
    __shared__ unsigned short Bs[128 * 32];
    const int tid = threadIdx.x;
    const int wid = tid >> 6, lane = tid & 63;
    const int lr = lane & 15, lg = lane >> 4;
    const int brow = blockIdx.y * 128, bcol = blockIdx.x * 128;
    const int wr = wid >> 1, wc = wid & 1;      // 2x2 waves, 64x64 each
    f32x4 acc[4][4] = {};

    for (int kt = 0; kt < K; kt += 32) {
#pragma unroll
        for (int i = 0; i < 2; ++i) {
            int f = i * 256 + tid;              // unit of 8 elems
            int row = f >> 2;
            int col8 = (f & 3) << 3;
            gload16(A + (size_t)(brow + row) * K + kt + col8,
                    As + (size_t)(i * 256 + wid * 64) * 8);
            gload16(BT + (size_t)(bcol + row) * K + kt + col8,
                    Bs + (size_t)(i * 256 + wid * 64) * 8);
        }
        __syncthreads();
        s8v a[4], b[4];
#pragma unroll
        for (int m = 0; m < 4; ++m)
            a[m] = *(const s8v*)(As + (size_t)(wr * 64 + m * 16 + lr) * 32 + lg * 8);
#pragma unroll
        for (int n = 0; n < 4; ++n)
            b[n] = *(const s8v*)(Bs + (size_t)(wc * 64 + n * 16 + lr) * 32 + lg * 8);
#pragma unroll
        for (int m = 0; m < 4; ++m)
#pragma unroll
            for (int n = 0; n < 4; ++n)
                acc[m][n] = __builtin_amdgcn_mfma_f32_16x16x32_bf16(a[m], b[n], acc[m][n], 0, 0, 0);
        __syncthreads();
    }
#pragma unroll
    for (int m = 0; m < 4; ++m)
#pragma unroll
        for (int n = 0; n < 4; ++n)
#pragma unroll
            for (int j = 0; j < 4; ++j) {
                int r = brow + wr * 64 + m * 16 + lg * 4 + j;
                int c = bcol + wc * 64 + n * 16 + lr;
                float v = acc[m][n][j];
                if constexpr (std::is_same<CT, float>::value)
                    C[(size_t)r * ldc + c] = v;
                else
                    C[(size_t)r * ldc + c] = f2bf(v);
            }
}

// ---------- RoPE in-place on qkv buffer [4096][3072]; q: cols 0..2047, k: 2048..2559 ----------
__global__ void rope_kernel(unsigned short* __restrict__ qkv,
                            const float* __restrict__ fc, const float* __restrict__ fs) {
    int idx = blockIdx.x * blockDim.x + threadIdx.x;   // 4096 * 20 * 16
    if (idx >= 4096 * 20 * 16) return;
    int grp = idx & 15;
    int hh = (idx >> 4) % 20;
    int row = idx / (16 * 20);
    int s = row & 2047;
    int col0 = (hh < 16 ? hh * 128 : 2048 + (hh - 16) * 128) + grp * 8;
    unsigned short* p = qkv + (size_t)row * 3072 + col0;
    s8v v = *(const s8v*)p;
    const float* cc = fc + (size_t)s * 64 + grp * 4;
    const float* ss = fs + (size_t)s * 64 + grp * 4;
#pragma unroll
    for (int j = 0; j < 4; ++j) {
        float xe = bf2f((unsigned short)v[2 * j]);
        float xo = bf2f((unsigned short)v[2 * j + 1]);
        float c = cc[j], sn = ss[j];
        v[2 * j]     = (short)f2bf(xe * c - xo * sn);
        v[2 * j + 1] = (short)f2bf(xe * sn + xo * c);
    }
    *(s8v*)p = v;
}

// ---------- Flash attention, GQA, causal — 32x32 MFMA, zero LDS, lane-local softmax ----
// 2048 blocks x 64 threads (1 wave). blockIdx&7 = (b,kvh) group -> one KV set per XCD.
// Wave owns 32 q rows (q = qw + lane&31). Swapped QK^T: S^T[key][q], C col = q lane-local.
// PV in out^T orientation: acc C col = q -> rescale/normalize lane-local.
// K frags read直接 from qkv (L2-resident 512KB/XCD); V^T frags from vtrans output.
__global__ __launch_bounds__(64, 2)
void attn_kernel(const unsigned short* __restrict__ qkv,
                 const unsigned short* __restrict__ vtg,
                 unsigned short* __restrict__ out) {
    constexpr int S = 2048;
    const int lane = threadIdx.x;
    const int l31 = lane & 31, h2 = lane >> 5;
    const int g8 = blockIdx.x & 7;
    const int b = g8 >> 2, kvh = g8 & 3;
    const int rest = blockIdx.x >> 3;
    const int gsub = rest & 3;
    const int qi = 63 - (rest >> 2);           // longest-first (LPT) dispatch order
    const int h = kvh * 4 + gsub;
    const int qw = qi * 32;
    const int qq = qw + l31;                   // this lane's q row
    const size_t rs = 3072;
    const float rscale = 0.08838834764831845f; // 1/sqrt(128)

    const unsigned short* Qp = qkv + (size_t)(b * S + qw) * rs + h * 128 + h2 * 8;
    const unsigned short* Kp = qkv + (size_t)(b * S) * rs + 2048 + kvh * 128 + h2 * 8;
    const unsigned short* Vp = vtg + (size_t)((b * 4 + kvh) * 128) * S + h2 * 8;

    // Q B-frag: col=q=l31, k = 16*kk + 8*h2 + e
    s8v qf[8];
#pragma unroll
    for (int kk = 0; kk < 8; ++kk)
        qf[kk] = *(const s8v*)(Qp + (size_t)l31 * rs + kk * 16);

    f32x16 acc[4] = {};                        // out^T: acc[dblk], row d, col q
    float m_run = -1e30f, l_run = 0.f;
    const int nt = (qi >> 1) + 1;

    for (int t = 0; t < nt; ++t) {
        const int kb64 = t * 64;
        // ---- K A-frags (row=key=l31+32g, k=16kk+8h2+e) + QK^T ----
        s8v kf0[8], kf1[8];
#pragma unroll
        for (int kk = 0; kk < 8; ++kk)
            kf0[kk] = *(const s8v*)(Kp + (size_t)(kb64 + l31) * rs + kk * 16);
#pragma unroll
        for (int kk = 0; kk < 8; ++kk)
            kf1[kk] = *(const s8v*)(Kp + (size_t)(kb64 + 32 + l31) * rs + kk * 16);
        f32x16 sacc0 = {}, sacc1 = {};
#pragma unroll
        for (int kk = 0; kk < 8; ++kk)
            sacc0 = __builtin_amdgcn_mfma_f32_32x32x16_bf16(kf0[kk], qf[kk], sacc0, 0, 0, 0);
#pragma unroll
        for (int kk = 0; kk < 8; ++kk)
            sacc1 = __builtin_amdgcn_mfma_f32_32x32x16_bf16(kf1[kk], qf[kk], sacc1, 0, 0, 0);

        // ---- V^T A-frags for PV (row=d, k=key), issued early to hide L2 latency ----
        s8v vf[4][4];
#pragma unroll
        for (int kb = 0; kb < 4; ++kb)
#pragma unroll
            for (int dblk = 0; dblk < 4; ++dblk)
                vf[kb][dblk] = *(const s8v*)(Vp + (size_t)(32 * dblk + l31) * S + kb64 + kb * 16);

        // ---- mask + scale: lane holds S[key(r,g)][q=qq] ----
        float sv[32];
#pragma unroll
        for (int g = 0; g < 2; ++g)
#pragma unroll
            for (int r = 0; r < 16; ++r) {
                int key = kb64 + 32 * g + (r & 3) + 8 * (r >> 2) + 4 * h2;
                float s = (g ? sacc1[r] : sacc0[r]) * rscale;
                sv[g * 16 + r] = (key <= qq) ? s : -1e30f;
            }

        // ---- online softmax, q lane-local; defer-max (THR=8) ----
        float mx = sv[0];
#pragma unroll
        for (int i = 1; i < 32; ++i) mx = fmaxf(mx, sv[i]);
        mx = fmaxf(mx, __shfl_xor(mx, 32));
        if (!__all(mx - m_run <= 8.f)) {
            float mn = fmaxf(m_run, mx);
            float alpha = __expf(m_run - mn);
            m_run = mn;
            l_run *= alpha;
#pragma unroll
            for (int dblk = 0; dblk < 4; ++dblk)
#pragma unroll
                for (int r = 0; r < 16; ++r) acc[dblk][r] *= alpha;
        }
        float ps = 0.f;
#pragma unroll
        for (int i = 0; i < 32; ++i) {
            float e = __expf(sv[i] - m_run);
            sv[i] = e;
            ps += e;
        }
        ps += __shfl_xor(ps, 32);
        l_run += ps;

        // ---- P -> B-frag (col=q, k=key): cvt_pk pairs + lane^32 exchange ----
        unsigned int pw[4][4];
#pragma unroll
        for (int g = 0; g < 2; ++g) {
            unsigned int w[8];
#pragma unroll
            for (int j = 0; j < 8; ++j)
                w[j] = cvtpk(sv[g * 16 + 2 * j], sv[g * 16 + 2 * j + 1]);
#pragma unroll
            for (int u = 0; u < 2; ++u) {
                unsigned int t0 = (unsigned)__shfl_xor((int)w[4 * u + 0], 32);
                unsigned int t1 = (unsigned)__shfl_xor((int)w[4 * u + 1], 32);
                unsigned int t2 = (unsigned)__shfl_xor((int)w[4 * u + 2], 32);
                unsigned int t3 = (unsigned)__shfl_xor((int)w[4 * u + 3], 32);
                pw[2 * g + u][0] = h2 ? t2 : w[4 * u + 0];
                pw[2 * g + u][1] = h2 ? t3 : w[4 * u + 1];
                pw[2 * g + u][2] = h2 ? w[4 * u + 2] : t0;
                pw[2 * g + u][3] = h2 ? w[4 * u + 3] : t1;
            }
        }

        // ---- PV: out^T[d][q] += V^T(32d x 16k) * P^T(16k x 32q) ----
#pragma unroll
        for (int kb = 0; kb < 4; ++kb) {
            u32x4 wv;
            wv[0] = pw[kb][0]; wv[1] = pw[kb][1]; wv[2] = pw[kb][2]; wv[3] = pw[kb][3];
            s8v pf = __builtin_bit_cast(s8v, wv);
#pragma unroll
            for (int dblk = 0; dblk < 4; ++dblk)
                acc[dblk] = __builtin_amdgcn_mfma_f32_32x32x16_bf16(vf[kb][dblk], pf, acc[dblk], 0, 0, 0);
        }
    }

    // ---- normalize (lane-local) and store out[q][h*128+d] ----
    float inv = 1.f / l_run;
    unsigned short* Op = out + (size_t)(b * S + qq) * 2048 + h * 128 + 4 * h2;
#pragma unroll
    for (int dblk = 0; dblk < 4; ++dblk)
#pragma unroll
        for (int s = 0; s < 4; ++s) {
            u32x2 wv;
            wv[0] = cvtpk(acc[dblk][4 * s + 0] * inv, acc[dblk][4 * s + 1] * inv);
            wv[1] = cvtpk(acc[dblk][4 * s + 2] * inv, acc[dblk][4 * s + 3] * inv);
            *(u32x2*)(Op + 32 * dblk + 8 * s) = wv;
        }
}

// ---------- launch ----------
extern "C" void kernel_launch(void* const* d_in, const int* in_sizes, int n_in,
                              void* d_out, int out_size, void* d_ws, size_t ws_size,
                              hipStream_t stream) {
    const float* x  = (const float*)d_in[0];
    const float* fc = (const float*)d_in[1];
    const float* fs = (const float*)d_in[2];
    const float* wq = (const float*)d_in[4];
    const float* wk = (const float*)d_in[5];
    const float* wv = (const float*)d_in[6];
    const float* wo = (const float*)d_in[7];
    float* out = (float*)d_out;

    char* ws = (char*)d_ws;
    unsigned short* xb    = (unsigned short*)ws;                               // 16 MB (reused as attn out)
    unsigned short* wqkvT = (unsigned short*)(ws + 16777216);                  // 12 MB (reused as V^T)
    unsigned short* woT   = (unsigned short*)(ws + 16777216 + 12582912);       // 8 MB
    unsigned short* qkvb  = (unsigned short*)(ws + 16777216 + 12582912 + 8388608); // 24 MB
    unsigned short* attnb = xb;
    unsigned short* vtb   = wqkvT;      // V^T [2][4][128][2048] = 4 MB, lives after gemm1

    conv_bf16<<<4096, 256, 0, stream>>>(x, xb, 1048576);
    dim3 tb(32, 8);
    transpose_conv<<<dim3(64, 64), tb, 0, stream>>>(wq, wqkvT, 2048, 2048);
    transpose_conv<<<dim3(16, 64), tb, 0, stream>>>(wk, wqkvT + (size_t)2048 * 2048, 2048, 512);
    transpose_conv<<<dim3(16, 64), tb, 0, stream>>>(wv, wqkvT + (size_t)2560 * 2048, 2048, 512);
    transpose_conv<<<dim3(64, 64), tb, 0, stream>>>(wo, woT, 2048, 2048);
    gemm_bt<unsigned short><<<dim3(24, 32), 256, 0, stream>>>(xb, wqkvT, qkvb, 4096, 3072, 2048, 3072);
    rope_kernel<<<5120, 256, 0, stream>>>(qkvb, fc, fs);
    vtrans<<<dim3(128, 16), tb, 0, stream>>>(qkvb, vtb);
    attn_kernel<<<2048, 64, 0, stream>>>(qkvb, vtb, attnb);
    gemm_bt<float><<<dim3(16, 32), 256, 0, stream>>>(attnb, woT, out, 4096, 2048, 2048, 2048);
}

// Round 6
// 258.926 us; speedup vs baseline: 1.5501x; 1.1392x over previous
//
#include <hip/hip_runtime.h>
#include <type_traits>

// ---------- types ----------
typedef short s8v   __attribute__((ext_vector_type(8)));   // 8 x bf16 bits
typedef float f32x4 __attribute__((ext_vector_type(4)));
typedef float f32x16 __attribute__((ext_vector_type(16)));
typedef unsigned int u32x2 __attribute__((ext_vector_type(2)));
typedef unsigned int u32x4 __attribute__((ext_vector_type(4)));

__device__ __forceinline__ unsigned short f2bf(float f) {
    unsigned int u = __builtin_bit_cast(unsigned int, f);
    u += 0x7FFF + ((u >> 16) & 1);          // round-to-nearest-even
    return (unsigned short)(u >> 16);
}
__device__ __forceinline__ float bf2f(unsigned short b) {
    unsigned int u = ((unsigned int)b) << 16;
    return __builtin_bit_cast(float, u);
}
__device__ __forceinline__ unsigned int cvtpk(float lo, float hi) {
    unsigned int w;
    asm("v_cvt_pk_bf16_f32 %0, %1, %2" : "=v"(w) : "v"(lo), "v"(hi));
    return w;
}

__device__ __forceinline__ void gload16(const void* g, void* l) {
    __builtin_amdgcn_global_load_lds(
        (const __attribute__((address_space(1))) void*)g,
        (__attribute__((address_space(3))) void*)l, 16, 0, 0);
}

// ---------- x -> bf16 (vectorized) ----------
__global__ void conv_bf16(const float* __restrict__ src, unsigned short* __restrict__ dst, int n8) {
    int i = blockIdx.x * blockDim.x + threadIdx.x;
    if (i >= n8) return;
    const f32x4* s4 = (const f32x4*)src;
    f32x4 a = s4[2 * i], b = s4[2 * i + 1];
    s8v o;
    o[0] = (short)f2bf(a[0]); o[1] = (short)f2bf(a[1]);
    o[2] = (short)f2bf(a[2]); o[3] = (short)f2bf(a[3]);
    o[4] = (short)f2bf(b[0]); o[5] = (short)f2bf(b[1]);
    o[6] = (short)f2bf(b[2]); o[7] = (short)f2bf(b[3]);
    *(s8v*)(dst + (size_t)i * 8) = o;
}

// ---------- W (KxN f32) -> W^T (NxK bf16) ----------
__global__ void transpose_conv(const float* __restrict__ src, unsigned short* __restrict__ dst,
                               int K, int N) {
    __shared__ float tile[32][33];
    int n0 = blockIdx.x * 32, k0 = blockIdx.y * 32;
    int tx = threadIdx.x, ty = threadIdx.y;     // 32 x 8
#pragma unroll
    for (int r = 0; r < 4; ++r)
        tile[ty + r * 8][tx] = src[(size_t)(k0 + ty + r * 8) * N + n0 + tx];
    __syncthreads();
#pragma unroll
    for (int r = 0; r < 4; ++r)
        dst[(size_t)(n0 + ty + r * 8) * K + k0 + tx] = f2bf(tile[tx][ty + r * 8]);
}

// ---------- V (cols 2560..3071 of qkv) -> V^T [b][kvh][128][2048] bf16 ----------
__global__ void vtrans(const unsigned short* __restrict__ qkv, unsigned short* __restrict__ vt) {
    __shared__ unsigned short t[32][33];
    int s0 = blockIdx.x * 32;          // global row 0..4095
    int c0 = blockIdx.y * 32;          // v-col 0..511
    int tx = threadIdx.x, ty = threadIdx.y;   // 32 x 8
#pragma unroll
    for (int r = 0; r < 4; ++r)
        t[ty + r * 8][tx] = qkv[(size_t)(s0 + ty + r * 8) * 3072 + 2560 + c0 + tx];
    __syncthreads();
    int b = s0 >> 11, s = s0 & 2047;
    size_t dbase = (size_t)(b * 4 + (c0 >> 7)) * 128 + (c0 & 127);
#pragma unroll
    for (int r = 0; r < 4; ++r)
        vt[(dbase + ty + r * 8) * 2048 + s + tx] = t[tx][ty + r * 8];
}

// ---------- GEMM: C(MxN) = A(MxK,bf16) * B^T(NxK,bf16), m97 structure ----------
template <typename CT>
__global__ __launch_bounds__(256)
void gemm_bt(const unsigned short* __restrict__ A, const unsigned short* __restrict__ BT,
             CT* __restrict__ C, int M, int N, int K, int ldc) {
    __shared__ unsigned short As[128 * 32];
    __shared__ unsigned short Bs[128 * 32];
    const int tid = threadIdx.x;
    const int wid = tid >> 6, lane = tid & 63;
    const int lr = lane & 15, lg = lane >> 4;
    const int brow = blockIdx.y * 128, bcol = blockIdx.x * 128;
    const int wr = wid >> 1, wc = wid & 1;      // 2x2 waves, 64x64 each
    f32x4 acc[4][4] = {};

    for (int kt = 0; kt < K; kt += 32) {
#pragma unroll
        for (int i = 0; i < 2; ++i) {
            int f = i * 256 + tid;              // unit of 8 elems
            int row = f >> 2;
            int col8 = (f & 3) << 3;
            gload16(A + (size_t)(brow + row) * K + kt + col8,
                    As + (size_t)(i * 256 + wid * 64) * 8);
            gload16(BT + (size_t)(bcol + row) * K + kt + col8,
                    Bs + (size_t)(i * 256 + wid * 64) * 8);
        }
        __syncthreads();
        s8v a[4], b[4];
#pragma unroll
        for (int m = 0; m < 4; ++m)
            a[m] = *(const s8v*)(As + (size_t)(wr * 64 + m * 16 + lr) * 32 + lg * 8);
#pragma unroll
        for (int n = 0; n < 4; ++n)
            b[n] = *(const s8v*)(Bs + (size_t)(wc * 64 + n * 16 + lr) * 32 + lg * 8);
#pragma unroll
        for (int m = 0; m < 4; ++m)
#pragma unroll
            for (int n = 0; n < 4; ++n)
                acc[m][n] = __builtin_amdgcn_mfma_f32_16x16x32_bf16(a[m], b[n], acc[m][n], 0, 0, 0);
        __syncthreads();
    }
#pragma unroll
    for (int m = 0; m < 4; ++m)
#pragma unroll
        for (int n = 0; n < 4; ++n)
#pragma unroll
            for (int j = 0; j < 4; ++j) {
                int r = brow + wr * 64 + m * 16 + lg * 4 + j;
                int c = bcol + wc * 64 + n * 16 + lr;
                float v = acc[m][n][j];
                if constexpr (std::is_same<CT, float>::value)
                    C[(size_t)r * ldc + c] = v;
                else
                    C[(size_t)r * ldc + c] = f2bf(v);
            }
}

// ---------- RoPE in-place on qkv buffer [4096][3072]; q: cols 0..2047, k: 2048..2559 ----------
__global__ void rope_kernel(unsigned short* __restrict__ qkv,
                            const float* __restrict__ fc, const float* __restrict__ fs) {
    int idx = blockIdx.x * blockDim.x + threadIdx.x;   // 4096 * 20 * 16
    if (idx >= 4096 * 20 * 16) return;
    int grp = idx & 15;
    int hh = (idx >> 4) % 20;
    int row = idx / (16 * 20);
    int s = row & 2047;
    int col0 = (hh < 16 ? hh * 128 : 2048 + (hh - 16) * 128) + grp * 8;
    unsigned short* p = qkv + (size_t)row * 3072 + col0;
    s8v v = *(const s8v*)p;
    const float* cc = fc + (size_t)s * 64 + grp * 4;
    const float* ss = fs + (size_t)s * 64 + grp * 4;
#pragma unroll
    for (int j = 0; j < 4; ++j) {
        float xe = bf2f((unsigned short)v[2 * j]);
        float xo = bf2f((unsigned short)v[2 * j + 1]);
        float c = cc[j], sn = ss[j];
        v[2 * j]     = (short)f2bf(xe * c - xo * sn);
        v[2 * j + 1] = (short)f2bf(xe * sn + xo * c);
    }
    *(s8v*)p = v;
}

// ---------- Flash attention, GQA, causal — 32x32 MFMA, LDS-staged KV, lane-local softmax --
// 512 blocks x 256 threads (4 waves). blockIdx&7 = (b,kvh) -> XCD-pinned KV (1MB/XCD L2).
// The 4 waves are the 4 q-heads sharing this kvh: ONE staged K/V tile feeds 4 heads.
// Each wave owns 32 q rows (q = qw + lane&31); swapped 32x32 QK^T keeps q lane-local
// (softmax/rescale/normalize lane-local; P->B-frag = 16 cvt_pk + 8 shfl_xor(32)).
// K and V^T staged via coalesced global_load_lds, both-sides XOR swizzle (rule 21)
// -> conflict-free ds_read_b128 fragment reads. KVBLK=64 double-buffered (64KB LDS).
__global__ __launch_bounds__(256)
void attn_kernel(const unsigned short* __restrict__ qkv,
                 const unsigned short* __restrict__ vtg,
                 unsigned short* __restrict__ out) {
    constexpr int S = 2048;
    __shared__ unsigned short Ks[2][64 * 128];   // [key][d-unit8 ^ (key&7)]
    __shared__ unsigned short Vs[2][128 * 64];   // [d][key-unit8 ^ (d&7)]
    const int tid = threadIdx.x, lane = tid & 63, wid = tid >> 6;
    const int l31 = lane & 31, h2 = lane >> 5;
    const int lsw = l31 & 7;
    const int g8 = blockIdx.x & 7;               // (b,kvh) -> XCD pin
    const int b = g8 >> 2, kvh = g8 & 3;
    const int qi = 63 - (blockIdx.x >> 3);       // longest-first (LPT)
    const int h = kvh * 4 + wid;                 // wave = head
    const int qw = qi * 32;
    const int qq = qw + l31;                     // this lane's q row
    const size_t rs = 3072;
    const float rscale = 0.08838834764831845f;   // 1/sqrt(128)

    const unsigned short* Qp = qkv + (size_t)(b * S + qw) * rs + h * 128 + h2 * 8;
    const unsigned short* Kbase = qkv + (size_t)(b * S) * rs + 2048 + kvh * 128;
    const unsigned short* Vtg = vtg + (size_t)((b * 4 + kvh) * 128) * S;

    // Q B-frag: col=q=l31, k = 16*kk + 8*h2 + e  (scattered, but once per kernel)
    s8v qf[8];
#pragma unroll
    for (int kk = 0; kk < 8; ++kk)
        qf[kk] = *(const s8v*)(Qp + (size_t)l31 * rs + kk * 16);

    f32x16 acc[4] = {};                          // out^T: acc[dblk], row d, col q
    float m_run = -1e30f, l_run = 0.f;
    const int nt = (qi >> 1) + 1;

    auto stage = [&](int t, int bufi) {
        const int kb64 = t * 64;
#pragma unroll
        for (int i = 0; i < 4; ++i) {            // K tile [64][128]: 1024 chunks of 16B
            int c = i * 256 + tid;
            int key = c >> 4, d8 = c & 15;
            gload16(Kbase + (size_t)(kb64 + key) * rs + ((d8 ^ (key & 7)) << 3),
                    &Ks[bufi][(size_t)c * 8]);
        }
#pragma unroll
        for (int i = 0; i < 4; ++i) {            // V^T tile [128][64]
            int c = i * 256 + tid;
            int d = c >> 3, k8 = c & 7;
            gload16(Vtg + (size_t)d * S + kb64 + ((k8 ^ (d & 7)) << 3),
                    &Vs[bufi][(size_t)c * 8]);
        }
    };

    int cur = 0;
    stage(0, 0);
    __syncthreads();

    for (int t = 0; t < nt; ++t) {
        if (t + 1 < nt) stage(t + 1, cur ^ 1);
        const int kb64 = t * 64;
        const char* Kb = (const char*)&Ks[cur][0];
        const char* Vb = (const char*)&Vs[cur][0];

        // ---- K A-frags from LDS (row=key, k=16kk+8h2+e); conflict-free swizzled ----
        s8v kf0[8], kf1[8];
#pragma unroll
        for (int kk = 0; kk < 8; ++kk)
            kf0[kk] = *(const s8v*)(Kb + l31 * 256 + (((2 * kk + h2) ^ lsw) << 4));
#pragma unroll
        for (int kk = 0; kk < 8; ++kk)
            kf1[kk] = *(const s8v*)(Kb + (32 + l31) * 256 + (((2 * kk + h2) ^ lsw) << 4));
        // ---- V^T A-frags (row=d=32dblk+l31, k=key=16kb+8h2+e) ----
        s8v vf[4][4];
#pragma unroll
        for (int kb = 0; kb < 4; ++kb)
#pragma unroll
            for (int dblk = 0; dblk < 4; ++dblk)
                vf[kb][dblk] = *(const s8v*)(Vb + (32 * dblk + l31) * 128 +
                                             (((2 * kb + h2) ^ lsw) << 4));

        // ---- QK^T (swapped): S^T[key][q], C col = q lane-local ----
        f32x16 sacc0 = {}, sacc1 = {};
        __builtin_amdgcn_s_setprio(1);
#pragma unroll
        for (int kk = 0; kk < 8; ++kk)
            sacc0 = __builtin_amdgcn_mfma_f32_32x32x16_bf16(kf0[kk], qf[kk], sacc0, 0, 0, 0);
#pragma unroll
        for (int kk = 0; kk < 8; ++kk)
            sacc1 = __builtin_amdgcn_mfma_f32_32x32x16_bf16(kf1[kk], qf[kk], sacc1, 0, 0, 0);
        __builtin_amdgcn_s_setprio(0);

        // ---- mask + scale: lane holds S[key(r,g)][q=qq] ----
        float sv[32];
#pragma unroll
        for (int g = 0; g < 2; ++g)
#pragma unroll
            for (int r = 0; r < 16; ++r) {
                int key = kb64 + 32 * g + (r & 3) + 8 * (r >> 2) + 4 * h2;
                float s = (g ? sacc1[r] : sacc0[r]) * rscale;
                sv[g * 16 + r] = (key <= qq) ? s : -1e30f;
            }

        // ---- online softmax, q lane-local; defer-max (THR=8) ----
        float mx = sv[0];
#pragma unroll
        for (int i = 1; i < 32; ++i) mx = fmaxf(mx, sv[i]);
        mx = fmaxf(mx, __shfl_xor(mx, 32));
        if (!__all(mx - m_run <= 8.f)) {
            float mn = fmaxf(m_run, mx);
            float alpha = __expf(m_run - mn);
            m_run = mn;
            l_run *= alpha;
#pragma unroll
            for (int dblk = 0; dblk < 4; ++dblk)
#pragma unroll
                for (int r = 0; r < 16; ++r) acc[dblk][r] *= alpha;
        }
        float ps = 0.f;
#pragma unroll
        for (int i = 0; i < 32; ++i) {
            float e = __expf(sv[i] - m_run);
            sv[i] = e;
            ps += e;
        }
        ps += __shfl_xor(ps, 32);
        l_run += ps;

        // ---- P -> B-frag (col=q, k=key): cvt_pk pairs + lane^32 exchange ----
        unsigned int pw[4][4];
#pragma unroll
        for (int g = 0; g < 2; ++g) {
            unsigned int w[8];
#pragma unroll
            for (int j = 0; j < 8; ++j)
                w[j] = cvtpk(sv[g * 16 + 2 * j], sv[g * 16 + 2 * j + 1]);
#pragma unroll
            for (int u = 0; u < 2; ++u) {
                unsigned int t0 = (unsigned)__shfl_xor((int)w[4 * u + 0], 32);
                unsigned int t1 = (unsigned)__shfl_xor((int)w[4 * u + 1], 32);
                unsigned int t2 = (unsigned)__shfl_xor((int)w[4 * u + 2], 32);
                unsigned int t3 = (unsigned)__shfl_xor((int)w[4 * u + 3], 32);
                pw[2 * g + u][0] = h2 ? t2 : w[4 * u + 0];
                pw[2 * g + u][1] = h2 ? t3 : w[4 * u + 1];
                pw[2 * g + u][2] = h2 ? w[4 * u + 2] : t0;
                pw[2 * g + u][3] = h2 ? w[4 * u + 3] : t1;
            }
        }

        // ---- PV: out^T[d][q] += V^T(32d x 16k) * P^T(16k x 32q) ----
        __builtin_amdgcn_s_setprio(1);
#pragma unroll
        for (int kb = 0; kb < 4; ++kb) {
            u32x4 wv;
            wv[0] = pw[kb][0]; wv[1] = pw[kb][1]; wv[2] = pw[kb][2]; wv[3] = pw[kb][3];
            s8v pf = __builtin_bit_cast(s8v, wv);
#pragma unroll
            for (int dblk = 0; dblk < 4; ++dblk)
                acc[dblk] = __builtin_amdgcn_mfma_f32_32x32x16_bf16(vf[kb][dblk], pf, acc[dblk], 0, 0, 0);
        }
        __builtin_amdgcn_s_setprio(0);

        __syncthreads();
        cur ^= 1;
    }

    // ---- normalize (lane-local) and store out[q][h*128+d] ----
    float inv = 1.f / l_run;
    unsigned short* Op = out + (size_t)(b * S + qq) * 2048 + h * 128 + 4 * h2;
#pragma unroll
    for (int dblk = 0; dblk < 4; ++dblk)
#pragma unroll
        for (int s = 0; s < 4; ++s) {
            u32x2 wv;
            wv[0] = cvtpk(acc[dblk][4 * s + 0] * inv, acc[dblk][4 * s + 1] * inv);
            wv[1] = cvtpk(acc[dblk][4 * s + 2] * inv, acc[dblk][4 * s + 3] * inv);
            *(u32x2*)(Op + 32 * dblk + 8 * s) = wv;
        }
}

// ---------- launch ----------
extern "C" void kernel_launch(void* const* d_in, const int* in_sizes, int n_in,
                              void* d_out, int out_size, void* d_ws, size_t ws_size,
                              hipStream_t stream) {
    const float* x  = (const float*)d_in[0];
    const float* fc = (const float*)d_in[1];
    const float* fs = (const float*)d_in[2];
    const float* wq = (const float*)d_in[4];
    const float* wk = (const float*)d_in[5];
    const float* wv = (const float*)d_in[6];
    const float* wo = (const float*)d_in[7];
    float* out = (float*)d_out;

    char* ws = (char*)d_ws;
    unsigned short* xb    = (unsigned short*)ws;                               // 16 MB (reused as attn out)
    unsigned short* wqkvT = (unsigned short*)(ws + 16777216);                  // 12 MB (reused as V^T)
    unsigned short* woT   = (unsigned short*)(ws + 16777216 + 12582912);       // 8 MB
    unsigned short* qkvb  = (unsigned short*)(ws + 16777216 + 12582912 + 8388608); // 24 MB
    unsigned short* attnb = xb;
    unsigned short* vtb   = wqkvT;      // V^T [2][4][128][2048] = 4 MB, lives after gemm1

    conv_bf16<<<4096, 256, 0, stream>>>(x, xb, 1048576);
    dim3 tb(32, 8);
    transpose_conv<<<dim3(64, 64), tb, 0, stream>>>(wq, wqkvT, 2048, 2048);
    transpose_conv<<<dim3(16, 64), tb, 0, stream>>>(wk, wqkvT + (size_t)2048 * 2048, 2048, 512);
    transpose_conv<<<dim3(16, 64), tb, 0, stream>>>(wv, wqkvT + (size_t)2560 * 2048, 2048, 512);
    transpose_conv<<<dim3(64, 64), tb, 0, stream>>>(wo, woT, 2048, 2048);
    gemm_bt<unsigned short><<<dim3(24, 32), 256, 0, stream>>>(xb, wqkvT, qkvb, 4096, 3072, 2048, 3072);
    rope_kernel<<<5120, 256, 0, stream>>>(qkvb, fc, fs);
    vtrans<<<dim3(128, 16), tb, 0, stream>>>(qkvb, vtb);
    attn_kernel<<<512, 256, 0, stream>>>(qkvb, vtb, attnb);
    gemm_bt<float><<<dim3(16, 32), 256, 0, stream>>>(attnb, woT, out, 4096, 2048, 2048, 2048);
}